// Round 1
// baseline (502.865 us; speedup 1.0000x reference)
//
#include <hip/hip_runtime.h>
#include <cmath>

typedef _Float16 f16x8 __attribute__((ext_vector_type(8)));
typedef _Float16 f16x4 __attribute__((ext_vector_type(4)));
typedef float    f32x4 __attribute__((ext_vector_type(4)));

#define LOG2E 1.4426950408889634f

// async global->LDS, 16B per lane. LDS dest must be wave-uniform base;
// HW writes base + lane*16. Global src is per-lane (we pre-swizzle it).
__device__ __forceinline__ void load_lds16(const void* g, void* l) {
  __builtin_amdgcn_global_load_lds(
      (const __attribute__((address_space(1))) unsigned int*)g,
      (__attribute__((address_space(3))) unsigned int*)l, 16, 0, 0);
}

// ---------------- fp32 -> fp16 convert ----------------
__global__ __launch_bounds__(256) void cvt_f32_f16(const float* __restrict__ in,
                                                   _Float16* __restrict__ out,
                                                   int n4) {
  int i = blockIdx.x * blockDim.x + threadIdx.x;
  int stride = gridDim.x * blockDim.x;
  for (; i < n4; i += stride) {
    float4 v = ((const float4*)in)[i];
    f16x4 h = { (_Float16)v.x, (_Float16)v.y, (_Float16)v.z, (_Float16)v.w };
    ((f16x4*)out)[i] = h;
  }
}

// ---------------- GEMM core: C[128x128] tile = A[128xK] * B[128xK]^T ----------------
// M=4096, N=2048, K=2048 fixed for all GEMMs in this problem.
// 4 waves, each owns a 64x64 subtile (4x4 of 16x16 frags), mfma_f32_16x16x32_f16.
// LDS tiles [128][32] fp16, 64B rows. XOR swizzle: 16B slot ^= (row&3),
// applied to the *global source* during global_load_lds (LDS stays linear)
// and to the ds_read address (involution).
__device__ __forceinline__ void gemm_core(const _Float16* __restrict__ A,
                                          const _Float16* __restrict__ B,
                                          _Float16* Asm, _Float16* Bsm,
                                          f32x4 acc[4][4]) {
  const int tid  = threadIdx.x;
  const int wave = tid >> 6, lane = tid & 63;
  const int g = lane >> 4, l15 = lane & 15;
  const int wm = wave >> 1, wn = wave & 1;
  const int srow = tid >> 2, sslot = tid & 3;

  const _Float16* Abase = A + (size_t)(blockIdx.x * 128) * 2048;
  const _Float16* Bbase = B + (size_t)(blockIdx.y * 128) * 2048;

  for (int k0 = 0; k0 < 2048; k0 += 32) {
#pragma unroll
    for (int i = 0; i < 2; ++i) {
      int row = i * 64 + srow;
      int sp  = sslot ^ (row & 3);
      load_lds16(Abase + (size_t)row * 2048 + k0 + sp * 8,
                 (char*)Asm + i * 4096 + wave * 1024);
      load_lds16(Bbase + (size_t)row * 2048 + k0 + sp * 8,
                 (char*)Bsm + i * 4096 + wave * 1024);
    }
    __syncthreads();

    f16x8 af[4], bf[4];
#pragma unroll
    for (int mi = 0; mi < 4; ++mi) {
      int row = wm * 64 + mi * 16 + l15;
      af[mi] = *(const f16x8*)((const char*)Asm + row * 64 + ((g ^ (row & 3)) << 4));
    }
#pragma unroll
    for (int ni = 0; ni < 4; ++ni) {
      int row = wn * 64 + ni * 16 + l15;
      bf[ni] = *(const f16x8*)((const char*)Bsm + row * 64 + ((g ^ (row & 3)) << 4));
    }
#pragma unroll
    for (int mi = 0; mi < 4; ++mi)
#pragma unroll
      for (int ni = 0; ni < 4; ++ni)
        acc[mi][ni] = __builtin_amdgcn_mfma_f32_16x16x32_f16(af[mi], bf[ni],
                                                             acc[mi][ni], 0, 0, 0);
    __syncthreads();
  }
}

// QKV projections fused into one launch: blockIdx.z selects weight/epilogue.
// Q is pre-scaled by SCALE*log2(e) so attention softmax can use exp2.
// Q,K written as fp16 [B,H,S,128]; V written transposed as fp16 [B,H,128,S].
__global__ __launch_bounds__(256) void gemm_qkv(
    const _Float16* __restrict__ Xh,
    const _Float16* __restrict__ Wq, const _Float16* __restrict__ Wk,
    const _Float16* __restrict__ Wv,
    _Float16* __restrict__ Qb, _Float16* __restrict__ Kb,
    _Float16* __restrict__ Vt, float qscale) {
  __shared__ _Float16 Asm[128 * 32], Bsm[128 * 32];
  const int z = blockIdx.z;
  const _Float16* B = (z == 0) ? Wq : (z == 1) ? Wk : Wv;
  f32x4 acc[4][4] = {};
  gemm_core(Xh, B, Asm, Bsm, acc);

  const int tid = threadIdx.x;
  const int wave = tid >> 6, lane = tid & 63;
  const int g = lane >> 4, l15 = lane & 15;
  const int wm = wave >> 1, wn = wave & 1;
  const float scale = (z == 0) ? qscale : 1.0f;
#pragma unroll
  for (int mi = 0; mi < 4; ++mi)
#pragma unroll
    for (int ni = 0; ni < 4; ++ni)
#pragma unroll
      for (int r = 0; r < 4; ++r) {
        int row = blockIdx.x * 128 + wm * 64 + mi * 16 + g * 4 + r;  // token
        int col = blockIdx.y * 128 + wn * 64 + ni * 16 + l15;        // feature
        float v = acc[mi][ni][r] * scale;
        int b = row >> 11, sq = row & 2047, h = col >> 7, d = col & 127;
        if (z < 2) {
          _Float16* dst = (z == 0) ? Qb : Kb;
          dst[(((size_t)b * 16 + h) * 2048 + sq) * 128 + d] = (_Float16)v;
        } else {
          Vt[(((size_t)b * 16 + h) * 128 + d) * 2048 + sq] = (_Float16)v;
        }
      }
}

// Final projection: AO[4096x2048] fp16 @ Wo^T -> fp32 out.
__global__ __launch_bounds__(256) void gemm_out(
    const _Float16* __restrict__ AO, const _Float16* __restrict__ Wo,
    float* __restrict__ C) {
  __shared__ _Float16 Asm[128 * 32], Bsm[128 * 32];
  f32x4 acc[4][4] = {};
  gemm_core(AO, Wo, Asm, Bsm, acc);

  const int tid = threadIdx.x;
  const int wave = tid >> 6, lane = tid & 63;
  const int g = lane >> 4, l15 = lane & 15;
  const int wm = wave >> 1, wn = wave & 1;
#pragma unroll
  for (int mi = 0; mi < 4; ++mi)
#pragma unroll
    for (int ni = 0; ni < 4; ++ni)
#pragma unroll
      for (int r = 0; r < 4; ++r) {
        int row = blockIdx.x * 128 + wm * 64 + mi * 16 + g * 4 + r;
        int col = blockIdx.y * 128 + wn * 64 + ni * 16 + l15;
        C[(size_t)row * 2048 + col] = acc[mi][ni][r];
      }
}

// ---------------- causal flash attention ----------------
// grid = (S/64, B*H). 4 waves x 16 q-rows. KV tile = 64 keys.
// Q in regs (pre-scaled to log2 domain); K staged [64][128] (swizzle slot^=(row&15));
// V staged from Vt as [128][64] (swizzle slot^=(row&7)); fp32 online softmax;
// P -> per-wave swizzled LDS [16][64] to convert C-layout -> A-frag layout.
__global__ __launch_bounds__(256) void attn_fwd(
    const _Float16* __restrict__ Qb, const _Float16* __restrict__ Kb,
    const _Float16* __restrict__ Vt, _Float16* __restrict__ AO) {
  const int qt = blockIdx.x, bh = blockIdx.y;
  const int tid = threadIdx.x;
  const int wave = tid >> 6, lane = tid & 63;
  const int g = lane >> 4, l15 = lane & 15;

  __shared__ _Float16 Ksm[64 * 128];   // 16 KB
  __shared__ _Float16 Vsm[128 * 64];   // 16 KB
  __shared__ char     Psm[4][2048];    // per-wave P tile [16][64] fp16, 8 KB

  // Q fragments: rows = qt*64 + wave*16 + (lane&15), 4 d-chunks of 32
  const _Float16* qp = Qb + ((size_t)bh * 2048 + qt * 64 + wave * 16 + l15) * 128;
  f16x8 qf[4];
#pragma unroll
  for (int c = 0; c < 4; ++c) qf[c] = *(const f16x8*)(qp + c * 32 + g * 8);

  f32x4 po[8] = {};
  float m[4], lsum[4];
#pragma unroll
  for (int r = 0; r < 4; ++r) { m[r] = -1e30f; lsum[r] = 0.f; }

  char* P = &Psm[wave][0];

  for (int t = 0; t <= qt; ++t) {
    // ---- stage K tile [64][128] and V tile [128][64] ----
#pragma unroll
    for (int i = 0; i < 4; ++i) {
      int krow = i * 16 + (tid >> 4);
      int ksp  = (tid & 15) ^ (krow & 15);
      load_lds16(Kb + ((size_t)bh * 2048 + t * 64 + krow) * 128 + ksp * 8,
                 (char*)Ksm + i * 4096 + wave * 1024);
      int vrow = i * 32 + (tid >> 3);
      int vsp  = (tid & 7) ^ (vrow & 7);
      load_lds16(Vt + ((size_t)bh * 128 + vrow) * 2048 + t * 64 + vsp * 8,
                 (char*)Vsm + i * 4096 + wave * 1024);
    }
    __syncthreads();

    // ---- S = Q K^T (log2 domain, Q pre-scaled) ----
    f32x4 s[4];
#pragma unroll
    for (int n = 0; n < 4; ++n) {
      f32x4 a = {0.f, 0.f, 0.f, 0.f};
#pragma unroll
      for (int c = 0; c < 4; ++c) {
        int krow = n * 16 + l15;
        int sp   = (c * 4 + g) ^ (krow & 15);
        f16x8 kf = *(const f16x8*)((const char*)Ksm + krow * 256 + (sp << 4));
        a = __builtin_amdgcn_mfma_f32_16x16x32_f16(qf[c], kf, a, 0, 0, 0);
      }
      s[n] = a;
    }

    // ---- causal mask on diagonal tile ----
    if (t == qt) {
#pragma unroll
      for (int n = 0; n < 4; ++n)
#pragma unroll
        for (int r = 0; r < 4; ++r) {
          int key = n * 16 + l15;
          int qr  = wave * 16 + g * 4 + r;
          if (key > qr) s[n][r] = -1e30f;
        }
    }

    // ---- online softmax (rows live in 16-lane groups) ----
#pragma unroll
    for (int r = 0; r < 4; ++r) {
      float mx = fmaxf(fmaxf(s[0][r], s[1][r]), fmaxf(s[2][r], s[3][r]));
#pragma unroll
      for (int off = 1; off < 16; off <<= 1) mx = fmaxf(mx, __shfl_xor(mx, off));
      float mn = fmaxf(m[r], mx);
      float sc = exp2f(m[r] - mn);
      m[r] = mn;
      float rs = 0.f;
#pragma unroll
      for (int n = 0; n < 4; ++n) {
        float p = exp2f(s[n][r] - mn);
        s[n][r] = p;
        rs += p;
      }
#pragma unroll
      for (int off = 1; off < 16; off <<= 1) rs += __shfl_xor(rs, off);
      lsum[r] = lsum[r] * sc + rs;
#pragma unroll
      for (int no = 0; no < 8; ++no) po[no][r] *= sc;
    }

    // ---- P (C-layout) -> LDS [16 q][64 key] fp16, swizzle slot^=(row&7) ----
#pragma unroll
    for (int n = 0; n < 4; ++n)
#pragma unroll
      for (int r = 0; r < 4; ++r) {
        int row = g * 4 + r, key = n * 16 + l15;
        int slot = key >> 3;
        *(_Float16*)(P + row * 128 + ((slot ^ (row & 7)) << 4) + (key & 7) * 2) =
            (_Float16)s[n][r];
      }

    // ---- PV: A-frags from P, B-frags from Vsm ----
    f16x8 pf[2];
#pragma unroll
    for (int kc = 0; kc < 2; ++kc) {
      int sp = (kc * 4 + g) ^ (l15 & 7);
      pf[kc] = *(const f16x8*)(P + l15 * 128 + (sp << 4));
    }
#pragma unroll
    for (int no = 0; no < 8; ++no)
#pragma unroll
      for (int kc = 0; kc < 2; ++kc) {
        int vrow = no * 16 + l15;
        int sp   = (kc * 4 + g) ^ (vrow & 7);
        f16x8 vf = *(const f16x8*)((const char*)Vsm + vrow * 128 + (sp << 4));
        po[no] = __builtin_amdgcn_mfma_f32_16x16x32_f16(pf[kc], vf, po[no], 0, 0, 0);
      }

    __syncthreads();  // before restaging K/V
  }

  // ---- normalize + store AO fp16 [4096][2048] (token, h*128+d) ----
  const int b = bh >> 4, h = bh & 15;
#pragma unroll
  for (int no = 0; no < 8; ++no)
#pragma unroll
    for (int r = 0; r < 4; ++r) {
      float v = po[no][r] / lsum[r];
      size_t row = (size_t)b * 2048 + qt * 64 + wave * 16 + g * 4 + r;
      int col = h * 128 + no * 16 + l15;
      AO[row * 2048 + col] = (_Float16)v;
    }
}

extern "C" void kernel_launch(void* const* d_in, const int* in_sizes, int n_in,
                              void* d_out, int out_size, void* d_ws, size_t ws_size,
                              hipStream_t stream) {
  const float* X  = (const float*)d_in[0];
  const float* Wq = (const float*)d_in[1];
  const float* Wk = (const float*)d_in[2];
  const float* Wv = (const float*)d_in[3];
  const float* Wo = (const float*)d_in[4];
  float* out = (float*)d_out;

  char* ws = (char*)d_ws;
  _Float16* Xh  = (_Float16*)(ws);                    // 16 MB
  _Float16* Wqh = (_Float16*)(ws + (16u << 20));      //  8 MB
  _Float16* Wkh = (_Float16*)(ws + (24u << 20));      //  8 MB
  _Float16* Wvh = (_Float16*)(ws + (32u << 20));      //  8 MB
  _Float16* Woh = (_Float16*)(ws + (40u << 20));      //  8 MB
  _Float16* Qb  = (_Float16*)(ws + (48u << 20));      // 16 MB [B,H,S,D]
  _Float16* Kb  = (_Float16*)(ws + (64u << 20));      // 16 MB [B,H,S,D]
  _Float16* Vt  = (_Float16*)(ws + (80u << 20));      // 16 MB [B,H,D,S]
  _Float16* AO  = (_Float16*)(ws + (96u << 20));      // 16 MB  -> 112 MB total

  cvt_f32_f16<<<2048, 256, 0, stream>>>(X,  Xh,  8388608 / 4);
  cvt_f32_f16<<<1024, 256, 0, stream>>>(Wq, Wqh, 4194304 / 4);
  cvt_f32_f16<<<1024, 256, 0, stream>>>(Wk, Wkh, 4194304 / 4);
  cvt_f32_f16<<<1024, 256, 0, stream>>>(Wv, Wvh, 4194304 / 4);
  cvt_f32_f16<<<1024, 256, 0, stream>>>(Wo, Woh, 4194304 / 4);

  const float qscale = LOG2E / sqrtf(128.0f);
  gemm_qkv<<<dim3(32, 16, 3), 256, 0, stream>>>(Xh, Wqh, Wkh, Wvh, Qb, Kb, Vt, qscale);
  attn_fwd<<<dim3(32, 32), 256, 0, stream>>>(Qb, Kb, Vt, AO);
  gemm_out<<<dim3(32, 16), 256, 0, stream>>>(AO, Woh, out);
}

// Round 4
// 449.902 us; speedup vs baseline: 1.1177x; 1.1177x over previous
//
#include <hip/hip_runtime.h>
#include <cmath>

typedef _Float16 f16x8 __attribute__((ext_vector_type(8)));
typedef _Float16 f16x4 __attribute__((ext_vector_type(4)));
typedef float    f32x4 __attribute__((ext_vector_type(4)));

#define LOG2E 1.4426950408889634f

// async global->LDS, 16B per lane. LDS dest is wave-uniform base + lane*16.
// Global src is per-lane (we pre-swizzle it so LDS stays linear).
__device__ __forceinline__ void load_lds16(const void* g, void* l) {
  __builtin_amdgcn_global_load_lds(
      (const __attribute__((address_space(1))) unsigned int*)g,
      (__attribute__((address_space(3))) unsigned int*)l, 16, 0, 0);
}

// ---------------- fp32 -> fp16 convert (X + 4 weights in 2 launches) ----------------
__global__ __launch_bounds__(256) void cvt_f32_f16(const float* __restrict__ in,
                                                   _Float16* __restrict__ out,
                                                   int n4) {
  int i = blockIdx.x * blockDim.x + threadIdx.x;
  int stride = gridDim.x * blockDim.x;
  for (; i < n4; i += stride) {
    float4 v = ((const float4*)in)[i];
    f16x4 h = { (_Float16)v.x, (_Float16)v.y, (_Float16)v.z, (_Float16)v.w };
    ((f16x4*)out)[i] = h;
  }
}

__global__ __launch_bounds__(256) void cvt_w4(const float* __restrict__ w0,
                                              const float* __restrict__ w1,
                                              const float* __restrict__ w2,
                                              const float* __restrict__ w3,
                                              _Float16* __restrict__ o0,
                                              _Float16* __restrict__ o1,
                                              _Float16* __restrict__ o2,
                                              _Float16* __restrict__ o3,
                                              int n4) {
  const float* in = (blockIdx.y == 0) ? w0 : (blockIdx.y == 1) ? w1
                  : (blockIdx.y == 2) ? w2 : w3;
  _Float16* out = (blockIdx.y == 0) ? o0 : (blockIdx.y == 1) ? o1
                : (blockIdx.y == 2) ? o2 : o3;
  int i = blockIdx.x * blockDim.x + threadIdx.x;
  int stride = gridDim.x * blockDim.x;
  for (; i < n4; i += stride) {
    float4 v = ((const float4*)in)[i];
    f16x4 h = { (_Float16)v.x, (_Float16)v.y, (_Float16)v.z, (_Float16)v.w };
    ((f16x4*)out)[i] = h;
  }
}

// ---------------- GEMM core: C[128x128] tile = A[128xK] * B[128xK]^T ----------------
__device__ __forceinline__ void gemm_core(const _Float16* __restrict__ A,
                                          const _Float16* __restrict__ B,
                                          _Float16* Asm, _Float16* Bsm,
                                          f32x4 acc[4][4]) {
  const int tid  = threadIdx.x;
  const int wave = tid >> 6, lane = tid & 63;
  const int g = lane >> 4, l15 = lane & 15;
  const int wm = wave >> 1, wn = wave & 1;
  const int srow = tid >> 2, sslot = tid & 3;

  const _Float16* Abase = A + (size_t)(blockIdx.x * 128) * 2048;
  const _Float16* Bbase = B + (size_t)(blockIdx.y * 128) * 2048;

  for (int k0 = 0; k0 < 2048; k0 += 32) {
#pragma unroll
    for (int i = 0; i < 2; ++i) {
      int row = i * 64 + srow;
      int sp  = sslot ^ (row & 3);
      load_lds16(Abase + (size_t)row * 2048 + k0 + sp * 8,
                 (char*)Asm + i * 4096 + wave * 1024);
      load_lds16(Bbase + (size_t)row * 2048 + k0 + sp * 8,
                 (char*)Bsm + i * 4096 + wave * 1024);
    }
    __syncthreads();

    f16x8 af[4], bf[4];
#pragma unroll
    for (int mi = 0; mi < 4; ++mi) {
      int row = wm * 64 + mi * 16 + l15;
      af[mi] = *(const f16x8*)((const char*)Asm + row * 64 + ((g ^ (row & 3)) << 4));
    }
#pragma unroll
    for (int ni = 0; ni < 4; ++ni) {
      int row = wn * 64 + ni * 16 + l15;
      bf[ni] = *(const f16x8*)((const char*)Bsm + row * 64 + ((g ^ (row & 3)) << 4));
    }
#pragma unroll
    for (int mi = 0; mi < 4; ++mi)
#pragma unroll
      for (int ni = 0; ni < 4; ++ni)
        acc[mi][ni] = __builtin_amdgcn_mfma_f32_16x16x32_f16(af[mi], bf[ni],
                                                             acc[mi][ni], 0, 0, 0);
    __syncthreads();
  }
}

// QKV projections fused: blockIdx.z selects weight/epilogue.
__global__ __launch_bounds__(256) void gemm_qkv(
    const _Float16* __restrict__ Xh,
    const _Float16* __restrict__ Wq, const _Float16* __restrict__ Wk,
    const _Float16* __restrict__ Wv,
    _Float16* __restrict__ Qb, _Float16* __restrict__ Kb,
    _Float16* __restrict__ Vt, float qscale) {
  __shared__ _Float16 Asm[128 * 32], Bsm[128 * 32];
  const int z = blockIdx.z;
  const _Float16* B = (z == 0) ? Wq : (z == 1) ? Wk : Wv;
  f32x4 acc[4][4] = {};
  gemm_core(Xh, B, Asm, Bsm, acc);

  const int tid = threadIdx.x;
  const int wave = tid >> 6, lane = tid & 63;
  const int g = lane >> 4, l15 = lane & 15;
  const int wm = wave >> 1, wn = wave & 1;
  const float scale = (z == 0) ? qscale : 1.0f;
#pragma unroll
  for (int mi = 0; mi < 4; ++mi)
#pragma unroll
    for (int ni = 0; ni < 4; ++ni)
#pragma unroll
      for (int r = 0; r < 4; ++r) {
        int row = blockIdx.x * 128 + wm * 64 + mi * 16 + g * 4 + r;  // token
        int col = blockIdx.y * 128 + wn * 64 + ni * 16 + l15;        // feature
        float v = acc[mi][ni][r] * scale;
        int b = row >> 11, sq = row & 2047, h = col >> 7, d = col & 127;
        if (z < 2) {
          _Float16* dst = (z == 0) ? Qb : Kb;
          dst[(((size_t)b * 16 + h) * 2048 + sq) * 128 + d] = (_Float16)v;
        } else {
          Vt[(((size_t)b * 16 + h) * 128 + d) * 2048 + sq] = (_Float16)v;
        }
      }
}

// Final projection: AO[4096x2048] fp16 @ Wo^T -> fp32 out.
__global__ __launch_bounds__(256) void gemm_out(
    const _Float16* __restrict__ AO, const _Float16* __restrict__ Wo,
    float* __restrict__ C) {
  __shared__ _Float16 Asm[128 * 32], Bsm[128 * 32];
  f32x4 acc[4][4] = {};
  gemm_core(AO, Wo, Asm, Bsm, acc);

  const int tid = threadIdx.x;
  const int wave = tid >> 6, lane = tid & 63;
  const int g = lane >> 4, l15 = lane & 15;
  const int wm = wave >> 1, wn = wave & 1;
#pragma unroll
  for (int mi = 0; mi < 4; ++mi)
#pragma unroll
    for (int ni = 0; ni < 4; ++ni)
#pragma unroll
      for (int r = 0; r < 4; ++r) {
        int row = blockIdx.x * 128 + wm * 64 + mi * 16 + g * 4 + r;
        int col = blockIdx.y * 128 + wn * 64 + ni * 16 + l15;
        C[(size_t)row * 2048 + col] = acc[mi][ni][r];
      }
}

// ---------------- causal flash attention ----------------
// QBLK=128 per block: 4 waves x 32 q-rows (2 row-frags). KV tile = 64 keys,
// double-buffered. One __syncthreads per tile: stage(t+1) -> compute(t) -> bar.
// XCD swizzle: 4 bh per XCD (K/V working set = 4MB = L2); reversed-qb dispatch
// fixes the triangular tail. Waves 0,1 skip the final (fully-masked) tile.
__global__ __launch_bounds__(256, 2) void attn_fwd(
    const _Float16* __restrict__ Qb, const _Float16* __restrict__ Kb,
    const _Float16* __restrict__ Vt, _Float16* __restrict__ AO) {
  const int id  = blockIdx.x;
  const int xcd = id & 7, j = id >> 3;
  const int bh  = xcd * 4 + (j & 3);
  const int qb  = 15 - (j >> 2);

  const int tid = threadIdx.x;
  const int wave = tid >> 6, lane = tid & 63;
  const int g = lane >> 4, l15 = lane & 15;

  __shared__ _Float16 Ksm[2][64 * 128];   // 32 KB
  __shared__ _Float16 Vsm[2][64 * 128];   // 32 KB ([128 d][64 key] per buf)
  __shared__ _Float16 Psm[4][32 * 64];    // 16 KB (per-wave P tile)

  // Q fragments: 32 rows per wave, 2 row-frags x 4 k-chunks
  const _Float16* qp =
      Qb + ((size_t)bh * 2048 + qb * 128 + wave * 32 + l15) * 128;
  f16x8 qf[2][4];
#pragma unroll
  for (int mi = 0; mi < 2; ++mi)
#pragma unroll
    for (int c = 0; c < 4; ++c)
      qf[mi][c] = *(const f16x8*)(qp + mi * 16 * 128 + c * 32 + g * 8);

  f32x4 po[2][8] = {};
  float m[2][4], lsum[2][4];
#pragma unroll
  for (int mi = 0; mi < 2; ++mi)
#pragma unroll
    for (int r = 0; r < 4; ++r) { m[mi][r] = -1e30f; lsum[mi][r] = 0.f; }

  char* Pb = (char*)&Psm[wave][0];
  const int NT  = 2 * qb + 2;               // KV tiles for this block
  const int NTw = 2 * qb + 1 + (wave >> 1); // tiles this wave computes
  const int dt  = 2 * qb + (wave >> 1);     // this wave's diagonal tile

  const int k_i  = tid >> 4, k_sp = (tid & 15) ^ (tid >> 4);
  const int v_i  = tid >> 3, v_sp = (tid & 7) ^ ((tid >> 3) & 7);
  const _Float16* kbase = Kb + (size_t)bh * 2048 * 128;
  const _Float16* vbase = Vt + (size_t)bh * 128 * 2048;

  auto stage = [&](int buf, int t) {
    char* kdst = (char*)&Ksm[buf][0] + wave * 1024;
    char* vdst = (char*)&Vsm[buf][0] + wave * 1024;
    const _Float16* kb = kbase + (size_t)t * 64 * 128;
    const _Float16* vb = vbase + t * 64;
#pragma unroll
    for (int i = 0; i < 4; ++i) {
      load_lds16(kb + (size_t)(i * 16 + k_i) * 128 + k_sp * 8, kdst + i * 4096);
      load_lds16(vb + (size_t)(i * 32 + v_i) * 2048 + v_sp * 8, vdst + i * 4096);
    }
  };

  stage(0, 0);
  __syncthreads();

  int buf = 0;
  for (int t = 0; t < NT; ++t) {
    if (t + 1 < NT) stage(buf ^ 1, t + 1);

    if (t < NTw) {
      const char* Kl = (const char*)&Ksm[buf][0];
      const char* Vl = (const char*)&Vsm[buf][0];

      // ---- S = Q K^T (log2 domain) ----
      f32x4 s[2][4];
#pragma unroll
      for (int n = 0; n < 4; ++n) {
        f32x4 a0 = {0.f, 0.f, 0.f, 0.f}, a1 = {0.f, 0.f, 0.f, 0.f};
#pragma unroll
        for (int c = 0; c < 4; ++c) {
          int slot = (c * 4 + g) ^ l15;
          f16x8 kf = *(const f16x8*)(Kl + (n * 16 + l15) * 256 + (slot << 4));
          a0 = __builtin_amdgcn_mfma_f32_16x16x32_f16(qf[0][c], kf, a0, 0, 0, 0);
          a1 = __builtin_amdgcn_mfma_f32_16x16x32_f16(qf[1][c], kf, a1, 0, 0, 0);
        }
        s[0][n] = a0; s[1][n] = a1;
      }

      // ---- causal mask on this wave's diagonal tile ----
      if (t == dt) {
#pragma unroll
        for (int mi = 0; mi < 2; ++mi)
#pragma unroll
          for (int n = 0; n < 4; ++n)
#pragma unroll
            for (int r = 0; r < 4; ++r) {
              int key = t * 64 + n * 16 + l15;
              int qr  = qb * 128 + wave * 32 + mi * 16 + g * 4 + r;
              if (key > qr) s[mi][n][r] = -1e30f;
            }
      }

      // ---- online softmax (rows in 16-lane groups) ----
#pragma unroll
      for (int mi = 0; mi < 2; ++mi)
#pragma unroll
        for (int r = 0; r < 4; ++r) {
          float mx = fmaxf(fmaxf(s[mi][0][r], s[mi][1][r]),
                           fmaxf(s[mi][2][r], s[mi][3][r]));
#pragma unroll
          for (int off = 1; off < 16; off <<= 1) mx = fmaxf(mx, __shfl_xor(mx, off));
          float mn = fmaxf(m[mi][r], mx);
          float sc = exp2f(m[mi][r] - mn);
          m[mi][r] = mn;
          float rs = 0.f;
#pragma unroll
          for (int n = 0; n < 4; ++n) {
            float p = exp2f(s[mi][n][r] - mn);
            s[mi][n][r] = p;
            rs += p;
          }
#pragma unroll
          for (int off = 1; off < 16; off <<= 1) rs += __shfl_xor(rs, off);
          lsum[mi][r] = lsum[mi][r] * sc + rs;
#pragma unroll
          for (int no = 0; no < 8; ++no) po[mi][no][r] *= sc;
        }

      // ---- P -> per-wave LDS [32 q][64 key], swizzle slot^=(row&7) ----
#pragma unroll
      for (int mi = 0; mi < 2; ++mi)
#pragma unroll
        for (int n = 0; n < 4; ++n)
#pragma unroll
          for (int r = 0; r < 4; ++r) {
            int row = mi * 16 + g * 4 + r, key = n * 16 + l15;
            *(_Float16*)(Pb + row * 128 + (((key >> 3) ^ (row & 7)) << 4) +
                         (key & 7) * 2) = (_Float16)s[mi][n][r];
          }

      // ---- PV ----
      f16x8 pf[2][2];
#pragma unroll
      for (int mi = 0; mi < 2; ++mi)
#pragma unroll
        for (int kc = 0; kc < 2; ++kc) {
          int slot = (kc * 4 + g) ^ (l15 & 7);
          pf[mi][kc] = *(const f16x8*)(Pb + (mi * 16 + l15) * 128 + (slot << 4));
        }
#pragma unroll
      for (int no = 0; no < 8; ++no)
#pragma unroll
        for (int kc = 0; kc < 2; ++kc) {
          int vrow = no * 16 + l15;
          int slot = (kc * 4 + g) ^ (l15 & 7);
          f16x8 vf = *(const f16x8*)(Vl + vrow * 128 + (slot << 4));
          po[0][no] = __builtin_amdgcn_mfma_f32_16x16x32_f16(pf[0][kc], vf,
                                                             po[0][no], 0, 0, 0);
          po[1][no] = __builtin_amdgcn_mfma_f32_16x16x32_f16(pf[1][kc], vf,
                                                             po[1][no], 0, 0, 0);
        }
    }

    __syncthreads();
    buf ^= 1;
  }

  // ---- normalize + store AO fp16 [4096][2048] ----
  const int b = bh >> 4, h = bh & 15;
#pragma unroll
  for (int mi = 0; mi < 2; ++mi)
#pragma unroll
    for (int r = 0; r < 4; ++r) {
      float inv = 1.0f / lsum[mi][r];
      size_t row = (size_t)b * 2048 + qb * 128 + wave * 32 + mi * 16 + g * 4 + r;
#pragma unroll
      for (int no = 0; no < 8; ++no) {
        int col = h * 128 + no * 16 + l15;
        AO[row * 2048 + col] = (_Float16)(po[mi][no][r] * inv);
      }
    }
}

extern "C" void kernel_launch(void* const* d_in, const int* in_sizes, int n_in,
                              void* d_out, int out_size, void* d_ws, size_t ws_size,
                              hipStream_t stream) {
  const float* X  = (const float*)d_in[0];
  const float* Wq = (const float*)d_in[1];
  const float* Wk = (const float*)d_in[2];
  const float* Wv = (const float*)d_in[3];
  const float* Wo = (const float*)d_in[4];
  float* out = (float*)d_out;

  char* ws = (char*)d_ws;
  _Float16* Xh  = (_Float16*)(ws);                    // 16 MB
  _Float16* Wqh = (_Float16*)(ws + (16u << 20));      //  8 MB
  _Float16* Wkh = (_Float16*)(ws + (24u << 20));      //  8 MB
  _Float16* Wvh = (_Float16*)(ws + (32u << 20));      //  8 MB
  _Float16* Woh = (_Float16*)(ws + (40u << 20));      //  8 MB
  _Float16* Qb  = (_Float16*)(ws + (48u << 20));      // 16 MB [B,H,S,D]
  _Float16* Kb  = (_Float16*)(ws + (64u << 20));      // 16 MB [B,H,S,D]
  _Float16* Vt  = (_Float16*)(ws + (80u << 20));      // 16 MB [B,H,D,S]
  _Float16* AO  = (_Float16*)(ws + (96u << 20));      // 16 MB -> 112 MB total

  cvt_f32_f16<<<2048, 256, 0, stream>>>(X, Xh, 8388608 / 4);
  cvt_w4<<<dim3(512, 4), 256, 0, stream>>>(Wq, Wk, Wv, Wo, Wqh, Wkh, Wvh, Woh,
                                           4194304 / 4);

  const float qscale = LOG2E / sqrtf(128.0f);
  gemm_qkv<<<dim3(32, 16, 3), 256, 0, stream>>>(Xh, Wqh, Wkh, Wvh, Qb, Kb, Vt, qscale);
  attn_fwd<<<512, 256, 0, stream>>>(Qb, Kb, Vt, AO);
  gemm_out<<<dim3(32, 16), 256, 0, stream>>>(AO, Woh, out);
}